// Round 12
// baseline (2098.242 us; speedup 1.0000x reference)
//
#include <hip/hip_runtime.h>

#define SEQ  2048
#define NB   8
#define HD   256
#define G3   768
#define NV   100
#define KVB  32

typedef float f32x4 __attribute__((ext_vector_type(4)));
typedef int   i32x4 __attribute__((ext_vector_type(4)));
typedef short s16x8 __attribute__((ext_vector_type(8)));

#define INV26 1.490116119384765625e-8f   // 2^-26

__device__ __forceinline__ float rcp_fast(float x) {
  return __builtin_amdgcn_rcpf(x);
}
__device__ __forceinline__ float sigm(float x) {
  x = fminf(fmaxf(x, -30.f), 30.f);
  return rcp_fast(1.f + __expf(-x));
}
__device__ __forceinline__ float tanh_fast(float x) {
  x = fminf(fmaxf(x, -15.f), 15.f);
  float e = __expf(2.f * x);
  return (e - 1.f) * rcp_fast(e + 1.f);
}
// split f32 into bf16 hi (truncate) + bf16 lo (truncated residual)
__device__ __forceinline__ void cvt_hilo(float f, unsigned short& h, unsigned short& l) {
  unsigned u = __float_as_uint(f);
  h = (unsigned short)(u >> 16);
  float r = f - __uint_as_float(u & 0xffff0000u);
  l = (unsigned short)(__float_as_uint(r) >> 16);
}

// ---------------- K1: xg lookup table, PACKED: table[(v*256+j)*4 + g]
__global__ __launch_bounds__(256) void build_table(
    const float* __restrict__ emb, const float* __restrict__ w_ih,
    const float* __restrict__ b_ih, float* __restrict__ table) {
  __shared__ float eL[256];
  __shared__ float wL[256][37];
  int v = blockIdx.x, tid = threadIdx.x;
  eL[tid] = emb[v * HD + tid];
  for (int gt = 0; gt < 3; ++gt) {
    float acc = b_ih[gt * 256 + tid];
    for (int e0 = 0; e0 < HD; e0 += 32) {
      __syncthreads();
      #pragma unroll
      for (int i = 0; i < 32; ++i) {
        int idx = tid + i * 256;
        int r = idx >> 5, c = idx & 31;
        wL[r][c] = w_ih[(size_t)(gt * 256 + r) * HD + e0 + c];
      }
      __syncthreads();
      #pragma unroll
      for (int c = 0; c < 32; ++c) acc += eL[e0 + c] * wL[tid][c];
    }
    table[((size_t)v * 256 + tid) * 4 + gt] = acc;
  }
}

// ---------------- K2: GRU scan — round-6 structure + LOAD-ONLY xg hoist.
// r6 exposed the xg table load's ~250cyc latency at its consumption right
// before the barrier (issue->use gap ~20 instr). Here the ISSUE moves to the
// top of the step (needs only xs[t+1]); consumption stays at the end ->
// ~1200cyc of MFMA+gate cover. The all_h store stays in its r6 place (r7's
// regression bundled a deferred store; that part is NOT repeated).
__global__ void __launch_bounds__(512) gru_scan(
    const int* __restrict__ x, const float* __restrict__ w_hh,
    const float* __restrict__ b_hh, const float* __restrict__ table,
    float* __restrict__ all_h, float* __restrict__ h_last) {
  __shared__ __align__(16) signed char hpk[2][2 * 272];  // [buf][plane*272]
  __shared__ int xs[SEQ];
  const int b = blockIdx.x;
  int tid = threadIdx.x;
  int lane = tid & 63, wv = tid >> 6;       // 8 waves
  int ncol = lane & 15, quad = lane >> 4;
  int usel = quad & 1;                      // which of the wave's 2 tiles
  int j = wv * 32 + usel * 16 + ncol;       // this lane's hidden unit

  for (int i = tid; i < SEQ; i += 512) xs[i] = x[b * SEQ + i];
  for (int i = tid; i < 2 * 272; i += 512)
    hpk[0][i] = (i >= 272) ? (signed char)-128 : 0;

  i32x4 bw[2][3][4];
  float Cn2[2][3];
  #pragma unroll
  for (int u = 0; u < 2; ++u) {
    #pragma unroll
    for (int t3 = 0; t3 < 3; ++t3) {
      int row = t3 * 256 + wv * 32 + u * 16 + ncol;
      int sw = 0;
      #pragma unroll
      for (int c = 0; c < 4; ++c) {
        const float* p = w_hh + (size_t)row * HD + c * 64 + quad * 16;
        unsigned pw[4] = {0u, 0u, 0u, 0u};
        #pragma unroll
        for (int e = 0; e < 16; ++e) {
          int q = __float2int_rn(p[e] * 2048.f);     // w * 2^11
          q = max(-127, min(127, q));
          sw += q;
          pw[e >> 2] |= ((unsigned)(q & 255)) << ((e & 3) * 8);
        }
        bw[u][t3][c] = (i32x4){(int)pw[0], (int)pw[1], (int)pw[2], (int)pw[3]};
      }
      sw += __shfl_xor(sw, 16);
      sw += __shfl_xor(sw, 32);
      Cn2[u][t3] = b_hh[row] + 128.f * (float)sw * INV26;
    }
  }
  float Csel[3];
  #pragma unroll
  for (int t3 = 0; t3 < 3; ++t3) Csel[t3] = usel ? Cn2[1][t3] : Cn2[0][t3];

  float hreg = 0.f;
  __syncthreads();
  float xr, xz, xn;
  {
    int v = xs[0];
    f32x4 xg = *(const f32x4*)&table[((size_t)v * 256 + j) * 4];
    xr = xg[0]; xz = xg[1]; xn = xg[2];
  }
  int a_base = (ncol & 1) * 272 + quad * 16;

  for (int t = 0; t < SEQ; ++t) {
    // ---- EARLY xg load issue (consumed at end of step, full-body cover)
    int vnext = xs[(t + 1 < SEQ) ? t + 1 : t];
    f32x4 xgn = *(const f32x4*)&table[((size_t)vnext * 256 + j) * 4];
    const signed char* cb = hpk[t & 1];
    i32x4 a[4];
    #pragma unroll
    for (int c = 0; c < 4; ++c)
      a[c] = *(const i32x4*)&cb[a_base + c * 64];
    float hg[3];
    #pragma unroll
    for (int t3 = 0; t3 < 3; ++t3) {
      i32x4 A0 = {0, 0, 0, 0}, A1 = {0, 0, 0, 0};
      #pragma unroll
      for (int c = 0; c < 4; ++c) {
        A0 = __builtin_amdgcn_mfma_i32_16x16x64_i8(a[c], bw[0][t3][c], A0, 0, 0, 0);
        A1 = __builtin_amdgcn_mfma_i32_16x16x64_i8(a[c], bw[1][t3][c], A1, 0, 0, 0);
      }
      int d0 = usel ? A1[0] : A0[0];
      int d1 = usel ? A1[1] : A0[1];
      hg[t3] = ((float)d0 * 256.f + (float)d1) * INV26 + Csel[t3];
    }
    float r = sigm(xr + hg[0]);
    float z = sigm(xz + hg[1]);
    float n = tanh_fast(xn + r * hg[2]);
    float h = (1.f - z) * n + z * hreg;
    hreg = h;
    int q = min(__float2int_rn(h * 32768.f), 32767);
    int lou = q & 255;
    int hi8 = (q - lou) >> 8;
    signed char* nx = hpk[(t + 1) & 1];
    if (quad < 2) {
      nx[j] = (signed char)hi8;
      nx[272 + j] = (signed char)(lou - 128);
      all_h[((size_t)b * SEQ + t) * HD + j] = h;
    }
    xr = xgn[0]; xz = xgn[1]; xn = xgn[2];   // prefetch landed long ago
    __syncthreads();
  }
  if (quad < 2) h_last[b * HD + j] = hreg;
}

// ---------------- generic f32 GEMM  C[M,N] = A[M,K]·W[N,K]^T + bias
template<int ACT>
__global__ __launch_bounds__(256) void gemm_bias(
    const float* __restrict__ A, int lda,
    const float* __restrict__ W, const float* __restrict__ bias,
    float* __restrict__ C, int ldc, int N, int K) {
  __shared__ float As[128][36];
  __shared__ float Ws[64][36];
  int tid = threadIdx.x;
  int m0 = blockIdx.y * 128, n0 = blockIdx.x * 64;
  int ml = tid & 31, g = tid >> 5;
  float acc[4][8];
  #pragma unroll
  for (int i = 0; i < 4; ++i)
    #pragma unroll
    for (int jj = 0; jj < 8; ++jj) acc[i][jj] = 0.f;
  for (int k0 = 0; k0 < K; k0 += 32) {
    __syncthreads();
    #pragma unroll
    for (int i = 0; i < 4; ++i) {
      int idx = tid + i * 256;
      int r = idx >> 3, c4 = (idx & 7) * 4;
      *(f32x4*)&As[r][c4] = *(const f32x4*)&A[(size_t)(m0 + r) * lda + k0 + c4];
    }
    #pragma unroll
    for (int i = 0; i < 2; ++i) {
      int idx = tid + i * 256;
      int r = idx >> 3, c4 = (idx & 7) * 4;
      f32x4 wv = {0.f, 0.f, 0.f, 0.f};
      if (n0 + r < N) wv = *(const f32x4*)&W[(size_t)(n0 + r) * K + k0 + c4];
      *(f32x4*)&Ws[r][c4] = wv;
    }
    __syncthreads();
    #pragma unroll
    for (int k4 = 0; k4 < 32; k4 += 4) {
      f32x4 av[4], wv8[8];
      #pragma unroll
      for (int i = 0; i < 4; ++i) av[i] = *(const f32x4*)&As[ml + i * 32][k4];
      #pragma unroll
      for (int jj = 0; jj < 8; ++jj) wv8[jj] = *(const f32x4*)&Ws[g * 8 + jj][k4];
      #pragma unroll
      for (int kk = 0; kk < 4; ++kk)
        #pragma unroll
        for (int i = 0; i < 4; ++i)
          #pragma unroll
          for (int jj = 0; jj < 8; ++jj)
            acc[i][jj] += av[i][kk] * wv8[jj][kk];
    }
  }
  #pragma unroll
  for (int i = 0; i < 4; ++i) {
    int m = m0 + ml + i * 32;
    #pragma unroll
    for (int jj = 0; jj < 8; ++jj) {
      int n = n0 + g * 8 + jj;
      if (n < N) {
        float val = acc[i][jj] + bias[n];
        if (ACT) val = tanh_fast(val);
        C[(size_t)m * ldc + n] = val;
      }
    }
  }
}

// ---------------- keys GEMM with PACKED bf16 hi/lo epilogue (round-8, verified)
__global__ __launch_bounds__(256) void gemm_keys_pack(
    const float* __restrict__ A,
    const float* __restrict__ W, const float* __restrict__ bias,
    unsigned short* __restrict__ KP) {
  __shared__ float As[128][36];
  __shared__ float Ws[64][36];
  const int K = 256;
  int tid = threadIdx.x;
  int m0 = blockIdx.y * 128, n0 = blockIdx.x * 64;
  int ml = tid & 31, gq = tid >> 5;
  float acc[4][8];
  #pragma unroll
  for (int i = 0; i < 4; ++i)
    #pragma unroll
    for (int jj = 0; jj < 8; ++jj) acc[i][jj] = 0.f;
  for (int k0 = 0; k0 < K; k0 += 32) {
    __syncthreads();
    #pragma unroll
    for (int i = 0; i < 4; ++i) {
      int idx = tid + i * 256;
      int r = idx >> 3, c4 = (idx & 7) * 4;
      *(f32x4*)&As[r][c4] = *(const f32x4*)&A[(size_t)(m0 + r) * HD + k0 + c4];
    }
    #pragma unroll
    for (int i = 0; i < 2; ++i) {
      int idx = tid + i * 256;
      int r = idx >> 3, c4 = (idx & 7) * 4;
      *(f32x4*)&Ws[r][c4] = *(const f32x4*)&W[(size_t)(n0 + r) * K + k0 + c4];
    }
    __syncthreads();
    #pragma unroll
    for (int k4 = 0; k4 < 32; k4 += 4) {
      f32x4 av[4], wv8[8];
      #pragma unroll
      for (int i = 0; i < 4; ++i) av[i] = *(const f32x4*)&As[ml + i * 32][k4];
      #pragma unroll
      for (int jj = 0; jj < 8; ++jj) wv8[jj] = *(const f32x4*)&Ws[gq * 8 + jj][k4];
      #pragma unroll
      for (int kk = 0; kk < 4; ++kk)
        #pragma unroll
        for (int i = 0; i < 4; ++i)
          #pragma unroll
          for (int jj = 0; jj < 8; ++jj)
            acc[i][jj] += av[i][kk] * wv8[jj][kk];
    }
  }
  #pragma unroll
  for (int i = 0; i < 4; ++i) {
    int m = m0 + ml + i * 32;
    int bb = m >> 11, key = m & 2047;
    int kt = key >> 5, g = (key >> 4) & 1, lmk = key & 15;
    int nb = n0 + gq * 8;                 // 8-aligned d-block
    int ch = nb >> 5, kq = (nb >> 3) & 3;
    size_t base = ((size_t)(bb * 64 + kt) * 32 + (g * 8 + ch) * 2) * 512
                + (size_t)(lmk + kq * 16) * 8;
    union { s16x8 v; unsigned short u[8]; } uh, ul;
    #pragma unroll
    for (int jj = 0; jj < 8; ++jj) {
      float val = acc[i][jj] + bias[nb + jj];
      cvt_hilo(val, uh.u[jj], ul.u[jj]);
    }
    *(s16x8*)&KP[base] = uh.v;            // hi plane unit
    *(s16x8*)&KP[base + 512] = ul.v;      // lo plane unit
  }
}

// ---------------- pack V = all_h into bf16 hi/lo B-frag layout (round-9, verified)
__global__ __launch_bounds__(256) void pack_v(
    const float* __restrict__ all_h, unsigned short* __restrict__ vp) {
  __shared__ float Lt[32][264];
  int b = blockIdx.y, kt = blockIdx.x, tid = threadIdx.x;
  const float* hb = all_h + (size_t)b * SEQ * HD + (size_t)kt * KVB * HD;
  #pragma unroll
  for (int i = 0; i < 8; ++i) {
    int idx = tid + i * 256;
    int r = idx >> 6, c = idx & 63;
    *(f32x4*)&Lt[r][c * 4] = *(const f32x4*)&hb[(size_t)r * HD + c * 4];
  }
  __syncthreads();
  unsigned short* vpt = vp + (size_t)(b * 64 + kt) * 16384;
  #pragma unroll
  for (int i = 0; i < 4; ++i) {
    int chunk = tid + i * 256;            // 0..1023
    int ht = chunk >> 6, l = chunk & 63;
    union { s16x8 v; unsigned short u[8]; } uh, ul;
    #pragma unroll
    for (int e = 0; e < 8; ++e) {
      float f = Lt[(l >> 4) * 8 + e][ht * 16 + (l & 15)];
      cvt_hilo(f, uh.u[e], ul.u[e]);
    }
    *(s16x8*)&vpt[(size_t)(ht * 2) * 512 + l * 8] = uh.v;
    *(s16x8*)&vpt[(size_t)(ht * 2 + 1) * 512 + l * 8] = ul.v;
  }
}

// ---------------- K4 v5: BARRIER-FREE causal flash attention.
// r11 post-mortem: with K AND V pre-packed in exact B-frag layout, the per-kt
// LDS bounce (2 barriers + ~80 LDS instr/wave/kt on the shared per-CU LDS
// pipe) buys nothing — a fragment read IS a coalesced 16B/lane global load.
// v5 keeps r11's 64-row WG (same total K/V traffic: each WG reads its key
// range exactly once) but reads frags DIRECTLY from global; KU/VU and all
// loop barriers deleted. LDS = per-wave PB only (8KB); __launch_bounds__
// (256,2) -> 2 waves/SIMD so TLP hides L3 latency (r9's neutral result was
// confounded: its 16-row WGs carried 4x the per-row traffic + a merge pass).
// Numerics bit-identical to r11 (same terms, same kt-ascending order).
__global__ __launch_bounds__(256, 2) void attention_kernel(
    const float* __restrict__ all_h, const unsigned short* __restrict__ kp,
    const unsigned short* __restrict__ vp, float* __restrict__ ctxg) {
  __shared__ __align__(16) unsigned short PB[4][2][520];
  const int b = blockIdx.y, qb = blockIdx.x;
  int tid = threadIdx.x, lane = tid & 63, wv = tid >> 6;
  int lm = lane & 15, kg = lane >> 4;
  const float* hb = all_h + (size_t)b * SEQ * HD;
  const unsigned short* kpb = kp + (size_t)b * 64 * 16384;
  const unsigned short* vpb = vp + (size_t)b * 64 * 16384;
  const int q0 = qb * 64 + wv * 16;        // wave's 16 q-rows

  // Q fragments (hi/lo): lane holds Q[q0+lm][ch*32 + kg*8 + e]
  s16x8 Qh[8], Ql[8];
  {
    const float* qp = hb + (size_t)(q0 + lm) * HD;
    #pragma unroll
    for (int ch = 0; ch < 8; ++ch) {
      union { s16x8 v; unsigned short u[8]; } uh, ul;
      f32x4 a0 = *(const f32x4*)&qp[ch * 32 + kg * 8];
      f32x4 a1 = *(const f32x4*)&qp[ch * 32 + kg * 8 + 4];
      #pragma unroll
      for (int e = 0; e < 4; ++e) {
        cvt_hilo(a0[e], uh.u[e], ul.u[e]);
        cvt_hilo(a1[e], uh.u[4 + e], ul.u[4 + e]);
      }
      Qh[ch] = uh.v; Ql[ch] = ul.v;
    }
  }

  f32x4 co[16];
  #pragma unroll
  for (int ht = 0; ht < 16; ++ht) co[ht] = (f32x4){0.f, 0.f, 0.f, 0.f};
  float mo[4] = {-3e38f, -3e38f, -3e38f, -3e38f};
  float lr[4] = {0.f, 0.f, 0.f, 0.f};

  const int nkt = 2 * qb + 2;
  for (int kt = 0; kt < nkt; ++kt) {
    const unsigned short* kpt = kpb + (size_t)kt * 16384;
    const unsigned short* vpt = vpb + (size_t)kt * 16384;
    int k0 = kt * KVB;

    // ---- QK^T: two 16-key groups, 3 hi/lo terms, frags direct from global
    float s[4][2];
    #pragma unroll
    for (int g = 0; g < 2; ++g) {
      f32x4 a0 = {0.f,0.f,0.f,0.f}, a1 = {0.f,0.f,0.f,0.f}, a2 = {0.f,0.f,0.f,0.f};
      #pragma unroll
      for (int ch = 0; ch < 8; ++ch) {
        const unsigned short* ub = &kpt[(size_t)((g * 8 + ch) * 2) * 512 + lane * 8];
        s16x8 bh = *(const s16x8*)ub;
        s16x8 bl = *(const s16x8*)(ub + 512);
        a0 = __builtin_amdgcn_mfma_f32_16x16x32_bf16(Qh[ch], bh, a0, 0, 0, 0);
        a1 = __builtin_amdgcn_mfma_f32_16x16x32_bf16(Ql[ch], bh, a1, 0, 0, 0);
        a2 = __builtin_amdgcn_mfma_f32_16x16x32_bf16(Qh[ch], bl, a2, 0, 0, 0);
      }
      #pragma unroll
      for (int r = 0; r < 4; ++r) s[r][g] = a0[r] + a1[r] + a2[r];
    }
    // ---- online softmax (q-row = kg*4+r; keys k0+lm, k0+16+lm)
    float p[4][2], al[4];
    #pragma unroll
    for (int r = 0; r < 4; ++r) {
      int qrow = q0 + kg * 4 + r;
      int va = (k0 + lm) <= qrow, vb = (k0 + 16 + lm) <= qrow;
      float ta = va ? s[r][0] : -3e38f;
      float tb = vb ? s[r][1] : -3e38f;
      float t = fmaxf(ta, tb);
      t = fmaxf(t, __shfl_xor(t, 1));
      t = fmaxf(t, __shfl_xor(t, 2));
      t = fmaxf(t, __shfl_xor(t, 4));
      t = fmaxf(t, __shfl_xor(t, 8));
      float mn = fmaxf(mo[r], t);
      al[r] = __expf(mo[r] - mn);
      float pa = va ? __expf(s[r][0] - mn) : 0.f;
      float pb = vb ? __expf(s[r][1] - mn) : 0.f;
      p[r][0] = pa; p[r][1] = pb;
      float rs = pa + pb;
      rs += __shfl_xor(rs, 1);
      rs += __shfl_xor(rs, 2);
      rs += __shfl_xor(rs, 4);
      rs += __shfl_xor(rs, 8);
      lr[r] = lr[r] * al[r] + rs;
      mo[r] = mn;
    }
    // ---- P -> A-frag via per-wave LDS (wave-internal, no barrier)
    #pragma unroll
    for (int r = 0; r < 4; ++r)
      #pragma unroll
      for (int g = 0; g < 2; ++g) {
        unsigned short ph, pl;
        cvt_hilo(p[r][g], ph, pl);
        int key = g * 16 + lm;
        int o = ((key >> 3) * 16 + kg * 4 + r) * 8 + (key & 7);
        PB[wv][0][o] = ph;
        PB[wv][1][o] = pl;
      }
    s16x8 pah = *(const s16x8*)&PB[wv][0][lane * 8];
    s16x8 pal = *(const s16x8*)&PB[wv][1][lane * 8];
    // ---- rescale + PV (V frags direct from global)
    #pragma unroll
    for (int ht = 0; ht < 16; ++ht) {
      f32x4 c = co[ht];
      #pragma unroll
      for (int r = 0; r < 4; ++r) c[r] *= al[r];
      const unsigned short* vb2 = &vpt[(size_t)(ht * 2) * 512 + lane * 8];
      s16x8 vh = *(const s16x8*)vb2;
      s16x8 vl = *(const s16x8*)(vb2 + 512);
      c = __builtin_amdgcn_mfma_f32_16x16x32_bf16(pah, vh, c, 0, 0, 0);
      c = __builtin_amdgcn_mfma_f32_16x16x32_bf16(pah, vl, c, 0, 0, 0);
      c = __builtin_amdgcn_mfma_f32_16x16x32_bf16(pal, vh, c, 0, 0, 0);
      co[ht] = c;
    }
  }
  float li[4];
  #pragma unroll
  for (int r = 0; r < 4; ++r) li[r] = rcp_fast(lr[r]);
  #pragma unroll
  for (int ht = 0; ht < 16; ++ht)
    #pragma unroll
    for (int r = 0; r < 4; ++r)
      ctxg[((size_t)b * SEQ + q0 + kg * 4 + r) * HD + ht * 16 + lm] = co[ht][r] * li[r];
}

// ---------------- comb GEMM: A = [all_h | ctx] split-K (K=512), tanh epilogue
__global__ __launch_bounds__(256) void gemm_bias_cat(
    const float* __restrict__ A1, const float* __restrict__ A2,
    const float* __restrict__ W, const float* __restrict__ bias,
    float* __restrict__ C) {
  __shared__ float As[128][36];
  __shared__ float Ws[64][36];
  const int K = 512;
  int tid = threadIdx.x;
  int m0 = blockIdx.y * 128, n0 = blockIdx.x * 64;
  int ml = tid & 31, g = tid >> 5;
  float acc[4][8];
  #pragma unroll
  for (int i = 0; i < 4; ++i)
    #pragma unroll
    for (int jj = 0; jj < 8; ++jj) acc[i][jj] = 0.f;
  for (int k0 = 0; k0 < K; k0 += 32) {
    const float* src = (k0 < 256) ? A1 : A2;
    int kb = (k0 < 256) ? k0 : k0 - 256;
    __syncthreads();
    #pragma unroll
    for (int i = 0; i < 4; ++i) {
      int idx = tid + i * 256;
      int r = idx >> 3, c4 = (idx & 7) * 4;
      *(f32x4*)&As[r][c4] = *(const f32x4*)&src[(size_t)(m0 + r) * 256 + kb + c4];
    }
    #pragma unroll
    for (int i = 0; i < 2; ++i) {
      int idx = tid + i * 256;
      int r = idx >> 3, c4 = (idx & 7) * 4;
      *(f32x4*)&Ws[r][c4] = *(const f32x4*)&W[(size_t)(n0 + r) * K + k0 + c4];
    }
    __syncthreads();
    #pragma unroll
    for (int k4 = 0; k4 < 32; k4 += 4) {
      f32x4 av[4], wv8[8];
      #pragma unroll
      for (int i = 0; i < 4; ++i) av[i] = *(const f32x4*)&As[ml + i * 32][k4];
      #pragma unroll
      for (int jj = 0; jj < 8; ++jj) wv8[jj] = *(const f32x4*)&Ws[g * 8 + jj][k4];
      #pragma unroll
      for (int kk = 0; kk < 4; ++kk)
        #pragma unroll
        for (int i = 0; i < 4; ++i)
          #pragma unroll
          for (int jj = 0; jj < 8; ++jj)
            acc[i][jj] += av[i][kk] * wv8[jj][kk];
    }
  }
  #pragma unroll
  for (int i = 0; i < 4; ++i) {
    int m = m0 + ml + i * 32;
    #pragma unroll
    for (int jj = 0; jj < 8; ++jj) {
      int n = n0 + g * 8 + jj;
      C[(size_t)m * 256 + n] = tanh_fast(acc[i][jj] + bias[n]);
    }
  }
}

extern "C" void kernel_launch(void* const* d_in, const int* in_sizes, int n_in,
                              void* d_out, int out_size, void* d_ws, size_t ws_size,
                              hipStream_t stream) {
  (void)in_sizes; (void)n_in; (void)out_size; (void)ws_size;
  const int*   x      = (const int*)  d_in[0];
  const float* emb    = (const float*)d_in[1];
  const float* w_ih   = (const float*)d_in[2];
  const float* w_hh   = (const float*)d_in[3];
  const float* b_ih   = (const float*)d_in[4];
  const float* b_hh   = (const float*)d_in[5];
  const float* attn_w = (const float*)d_in[6];
  const float* attn_b = (const float*)d_in[7];
  const float* comb_w = (const float*)d_in[8];
  const float* comb_b = (const float*)d_in[9];
  const float* fc_w   = (const float*)d_in[10];
  const float* fc_b   = (const float*)d_in[11];
  float* out = (float*)d_out;

  // workspace (floats): table | all_h | kp(packed K) | ctx | vp(packed V)
  float* ws    = (float*)d_ws;
  float* table = ws;                        // 100*256*4    =   102400
  float* all_h = table + 102400;            // 16384*256    =  4194304
  float* keysb = all_h + 4194304;           //               4194304 (shorts: packed K; later combined)
  float* ctx   = keysb + 4194304;           //               4194304
  float* vbuf  = ctx + 4194304;             //               4194304 (shorts: packed V)
  float* hlast = out + (size_t)NB * SEQ * NV;
  unsigned short* kpack = (unsigned short*)keysb;
  unsigned short* vpack = (unsigned short*)vbuf;

  build_table<<<100, 256, 0, stream>>>(emb, w_ih, b_ih, table);
  gru_scan<<<NB, 512, 0, stream>>>(x, w_hh, b_hh, table, all_h, hlast);
  // packed keys = pack(all_h @ attn_w^T + attn_b)
  gemm_keys_pack<<<dim3(4, 128), 256, 0, stream>>>(all_h, attn_w, attn_b, kpack);
  // packed V = pack(all_h)
  pack_v<<<dim3(64, NB), 256, 0, stream>>>(all_h, vpack);
  // ctx = softmax(causal(all_h @ keys^T)) @ all_h   (barrier-free bf16x3 attn)
  attention_kernel<<<dim3(32, NB), 256, 0, stream>>>(all_h, kpack, vpack, ctx);
  // combined = tanh([all_h|ctx] @ comb_w^T + comb_b)  (into keys buffer region)
  gemm_bias_cat<<<dim3(4, 128), 256, 0, stream>>>(all_h, ctx, comb_w, comb_b, keysb);
  // out = combined @ fc_w^T + fc_b
  gemm_bias<0><<<dim3(2, 128), 256, 0, stream>>>(keysb, 256, fc_w, fc_b, out, 100, 100, 256);
}

// Round 13
// 1845.858 us; speedup vs baseline: 1.1367x; 1.1367x over previous
//
#include <hip/hip_runtime.h>

#define SEQ  2048
#define NB   8
#define HD   256
#define G3   768
#define NV   100
#define KVB  32

typedef float f32x4 __attribute__((ext_vector_type(4)));
typedef int   i32x4 __attribute__((ext_vector_type(4)));
typedef short s16x8 __attribute__((ext_vector_type(8)));

#define INV26 1.490116119384765625e-8f   // 2^-26

__device__ __forceinline__ float rcp_fast(float x) {
  return __builtin_amdgcn_rcpf(x);
}
__device__ __forceinline__ float sigm(float x) {
  x = fminf(fmaxf(x, -30.f), 30.f);
  return rcp_fast(1.f + __expf(-x));
}
__device__ __forceinline__ float tanh_fast(float x) {
  x = fminf(fmaxf(x, -15.f), 15.f);
  float e = __expf(2.f * x);
  return (e - 1.f) * rcp_fast(e + 1.f);
}
// split f32 into bf16 hi (truncate) + bf16 lo (truncated residual)
__device__ __forceinline__ void cvt_hilo(float f, unsigned short& h, unsigned short& l) {
  unsigned u = __float_as_uint(f);
  h = (unsigned short)(u >> 16);
  float r = f - __uint_as_float(u & 0xffff0000u);
  l = (unsigned short)(__float_as_uint(r) >> 16);
}

// ---------------- K1: xg lookup table, PACKED: table[(v*256+j)*4 + g]
__global__ __launch_bounds__(256) void build_table(
    const float* __restrict__ emb, const float* __restrict__ w_ih,
    const float* __restrict__ b_ih, float* __restrict__ table) {
  __shared__ float eL[256];
  __shared__ float wL[256][37];
  int v = blockIdx.x, tid = threadIdx.x;
  eL[tid] = emb[v * HD + tid];
  for (int gt = 0; gt < 3; ++gt) {
    float acc = b_ih[gt * 256 + tid];
    for (int e0 = 0; e0 < HD; e0 += 32) {
      __syncthreads();
      #pragma unroll
      for (int i = 0; i < 32; ++i) {
        int idx = tid + i * 256;
        int r = idx >> 5, c = idx & 31;
        wL[r][c] = w_ih[(size_t)(gt * 256 + r) * HD + e0 + c];
      }
      __syncthreads();
      #pragma unroll
      for (int c = 0; c < 32; ++c) acc += eL[e0 + c] * wL[tid][c];
    }
    table[((size_t)v * 256 + tid) * 4 + gt] = acc;
  }
}

// ---------------- K2: GRU scan — EXACT round-6 version (1236us, VGPR 76).
// DISPROVEN variants (do not retry): r1 1-WG fuse (VALU-bound), r4 4-wave
// (spill), r7+r12 early xg-issue (lengthens chain: 1239->1271/1388).
// Per-CU VALU(48%)+MFMA(52%) ~ 100% serialized by the recurrence: structural
// floor of this decomposition.
__global__ void __launch_bounds__(512) gru_scan(
    const int* __restrict__ x, const float* __restrict__ w_hh,
    const float* __restrict__ b_hh, const float* __restrict__ table,
    float* __restrict__ all_h, float* __restrict__ h_last) {
  __shared__ __align__(16) signed char hpk[2][2 * 272];  // [buf][plane*272]
  __shared__ int xs[SEQ];
  const int b = blockIdx.x;
  int tid = threadIdx.x;
  int lane = tid & 63, wv = tid >> 6;       // 8 waves
  int ncol = lane & 15, quad = lane >> 4;
  int usel = quad & 1;                      // which of the wave's 2 tiles
  int j = wv * 32 + usel * 16 + ncol;       // this lane's hidden unit

  for (int i = tid; i < SEQ; i += 512) xs[i] = x[b * SEQ + i];
  for (int i = tid; i < 2 * 272; i += 512)
    hpk[0][i] = (i >= 272) ? (signed char)-128 : 0;

  i32x4 bw[2][3][4];
  float Cn2[2][3];
  #pragma unroll
  for (int u = 0; u < 2; ++u) {
    #pragma unroll
    for (int t3 = 0; t3 < 3; ++t3) {
      int row = t3 * 256 + wv * 32 + u * 16 + ncol;
      int sw = 0;
      #pragma unroll
      for (int c = 0; c < 4; ++c) {
        const float* p = w_hh + (size_t)row * HD + c * 64 + quad * 16;
        unsigned pw[4] = {0u, 0u, 0u, 0u};
        #pragma unroll
        for (int e = 0; e < 16; ++e) {
          int q = __float2int_rn(p[e] * 2048.f);     // w * 2^11
          q = max(-127, min(127, q));
          sw += q;
          pw[e >> 2] |= ((unsigned)(q & 255)) << ((e & 3) * 8);
        }
        bw[u][t3][c] = (i32x4){(int)pw[0], (int)pw[1], (int)pw[2], (int)pw[3]};
      }
      sw += __shfl_xor(sw, 16);
      sw += __shfl_xor(sw, 32);
      Cn2[u][t3] = b_hh[row] + 128.f * (float)sw * INV26;
    }
  }
  float Csel[3];
  #pragma unroll
  for (int t3 = 0; t3 < 3; ++t3) Csel[t3] = usel ? Cn2[1][t3] : Cn2[0][t3];

  float hreg = 0.f;
  __syncthreads();
  float xr, xz, xn;
  {
    int v = xs[0];
    f32x4 xg = *(const f32x4*)&table[((size_t)v * 256 + j) * 4];
    xr = xg[0]; xz = xg[1]; xn = xg[2];
  }
  int a_base = (ncol & 1) * 272 + quad * 16;

  for (int t = 0; t < SEQ; ++t) {
    const signed char* cb = hpk[t & 1];
    i32x4 a[4];
    #pragma unroll
    for (int c = 0; c < 4; ++c)
      a[c] = *(const i32x4*)&cb[a_base + c * 64];
    float hg[3];
    #pragma unroll
    for (int t3 = 0; t3 < 3; ++t3) {
      i32x4 A0 = {0, 0, 0, 0}, A1 = {0, 0, 0, 0};
      #pragma unroll
      for (int c = 0; c < 4; ++c) {
        A0 = __builtin_amdgcn_mfma_i32_16x16x64_i8(a[c], bw[0][t3][c], A0, 0, 0, 0);
        A1 = __builtin_amdgcn_mfma_i32_16x16x64_i8(a[c], bw[1][t3][c], A1, 0, 0, 0);
      }
      int d0 = usel ? A1[0] : A0[0];
      int d1 = usel ? A1[1] : A0[1];
      hg[t3] = ((float)d0 * 256.f + (float)d1) * INV26 + Csel[t3];
    }
    float r = sigm(xr + hg[0]);
    float z = sigm(xz + hg[1]);
    float n = tanh_fast(xn + r * hg[2]);
    float h = (1.f - z) * n + z * hreg;
    hreg = h;
    int q = min(__float2int_rn(h * 32768.f), 32767);
    int lou = q & 255;
    int hi8 = (q - lou) >> 8;
    signed char* nx = hpk[(t + 1) & 1];
    if (quad < 2) {
      nx[j] = (signed char)hi8;
      nx[272 + j] = (signed char)(lou - 128);
      all_h[((size_t)b * SEQ + t) * HD + j] = h;
    }
    int v = xs[(t + 1 < SEQ) ? t + 1 : t];
    f32x4 xg = *(const f32x4*)&table[((size_t)v * 256 + j) * 4];
    xr = xg[0]; xz = xg[1]; xn = xg[2];
    __syncthreads();
  }
  if (quad < 2) h_last[b * HD + j] = hreg;
}

// ---------------- generic f32 GEMM  C[M,N] = A[M,K]·W[N,K]^T + bias
template<int ACT>
__global__ __launch_bounds__(256) void gemm_bias(
    const float* __restrict__ A, int lda,
    const float* __restrict__ W, const float* __restrict__ bias,
    float* __restrict__ C, int ldc, int N, int K) {
  __shared__ float As[128][36];
  __shared__ float Ws[64][36];
  int tid = threadIdx.x;
  int m0 = blockIdx.y * 128, n0 = blockIdx.x * 64;
  int ml = tid & 31, g = tid >> 5;
  float acc[4][8];
  #pragma unroll
  for (int i = 0; i < 4; ++i)
    #pragma unroll
    for (int jj = 0; jj < 8; ++jj) acc[i][jj] = 0.f;
  for (int k0 = 0; k0 < K; k0 += 32) {
    __syncthreads();
    #pragma unroll
    for (int i = 0; i < 4; ++i) {
      int idx = tid + i * 256;
      int r = idx >> 3, c4 = (idx & 7) * 4;
      *(f32x4*)&As[r][c4] = *(const f32x4*)&A[(size_t)(m0 + r) * lda + k0 + c4];
    }
    #pragma unroll
    for (int i = 0; i < 2; ++i) {
      int idx = tid + i * 256;
      int r = idx >> 3, c4 = (idx & 7) * 4;
      f32x4 wv = {0.f, 0.f, 0.f, 0.f};
      if (n0 + r < N) wv = *(const f32x4*)&W[(size_t)(n0 + r) * K + k0 + c4];
      *(f32x4*)&Ws[r][c4] = wv;
    }
    __syncthreads();
    #pragma unroll
    for (int k4 = 0; k4 < 32; k4 += 4) {
      f32x4 av[4], wv8[8];
      #pragma unroll
      for (int i = 0; i < 4; ++i) av[i] = *(const f32x4*)&As[ml + i * 32][k4];
      #pragma unroll
      for (int jj = 0; jj < 8; ++jj) wv8[jj] = *(const f32x4*)&Ws[g * 8 + jj][k4];
      #pragma unroll
      for (int kk = 0; kk < 4; ++kk)
        #pragma unroll
        for (int i = 0; i < 4; ++i)
          #pragma unroll
          for (int jj = 0; jj < 8; ++jj)
            acc[i][jj] += av[i][kk] * wv8[jj][kk];
    }
  }
  #pragma unroll
  for (int i = 0; i < 4; ++i) {
    int m = m0 + ml + i * 32;
    #pragma unroll
    for (int jj = 0; jj < 8; ++jj) {
      int n = n0 + g * 8 + jj;
      if (n < N) {
        float val = acc[i][jj] + bias[n];
        if (ACT) val = tanh_fast(val);
        C[(size_t)m * ldc + n] = val;
      }
    }
  }
}

// ---------------- keys GEMM with PACKED bf16 hi/lo epilogue (round-8, verified)
__global__ __launch_bounds__(256) void gemm_keys_pack(
    const float* __restrict__ A,
    const float* __restrict__ W, const float* __restrict__ bias,
    unsigned short* __restrict__ KP) {
  __shared__ float As[128][36];
  __shared__ float Ws[64][36];
  const int K = 256;
  int tid = threadIdx.x;
  int m0 = blockIdx.y * 128, n0 = blockIdx.x * 64;
  int ml = tid & 31, gq = tid >> 5;
  float acc[4][8];
  #pragma unroll
  for (int i = 0; i < 4; ++i)
    #pragma unroll
    for (int jj = 0; jj < 8; ++jj) acc[i][jj] = 0.f;
  for (int k0 = 0; k0 < K; k0 += 32) {
    __syncthreads();
    #pragma unroll
    for (int i = 0; i < 4; ++i) {
      int idx = tid + i * 256;
      int r = idx >> 3, c4 = (idx & 7) * 4;
      *(f32x4*)&As[r][c4] = *(const f32x4*)&A[(size_t)(m0 + r) * HD + k0 + c4];
    }
    #pragma unroll
    for (int i = 0; i < 2; ++i) {
      int idx = tid + i * 256;
      int r = idx >> 3, c4 = (idx & 7) * 4;
      *(f32x4*)&Ws[r][c4] = *(const f32x4*)&W[(size_t)(n0 + r) * K + k0 + c4];
    }
    __syncthreads();
    #pragma unroll
    for (int k4 = 0; k4 < 32; k4 += 4) {
      f32x4 av[4], wv8[8];
      #pragma unroll
      for (int i = 0; i < 4; ++i) av[i] = *(const f32x4*)&As[ml + i * 32][k4];
      #pragma unroll
      for (int jj = 0; jj < 8; ++jj) wv8[jj] = *(const f32x4*)&Ws[gq * 8 + jj][k4];
      #pragma unroll
      for (int kk = 0; kk < 4; ++kk)
        #pragma unroll
        for (int i = 0; i < 4; ++i)
          #pragma unroll
          for (int jj = 0; jj < 8; ++jj)
            acc[i][jj] += av[i][kk] * wv8[jj][kk];
    }
  }
  #pragma unroll
  for (int i = 0; i < 4; ++i) {
    int m = m0 + ml + i * 32;
    int bb = m >> 11, key = m & 2047;
    int kt = key >> 5, g = (key >> 4) & 1, lmk = key & 15;
    int nb = n0 + gq * 8;                 // 8-aligned d-block
    int ch = nb >> 5, kq = (nb >> 3) & 3;
    size_t base = ((size_t)(bb * 64 + kt) * 32 + (g * 8 + ch) * 2) * 512
                + (size_t)(lmk + kq * 16) * 8;
    union { s16x8 v; unsigned short u[8]; } uh, ul;
    #pragma unroll
    for (int jj = 0; jj < 8; ++jj) {
      float val = acc[i][jj] + bias[nb + jj];
      cvt_hilo(val, uh.u[jj], ul.u[jj]);
    }
    *(s16x8*)&KP[base] = uh.v;            // hi plane unit
    *(s16x8*)&KP[base + 512] = ul.v;      // lo plane unit
  }
}

// ---------------- pack V = all_h into bf16 hi/lo B-frag layout (round-9, verified)
__global__ __launch_bounds__(256) void pack_v(
    const float* __restrict__ all_h, unsigned short* __restrict__ vp) {
  __shared__ float Lt[32][264];
  int b = blockIdx.y, kt = blockIdx.x, tid = threadIdx.x;
  const float* hb = all_h + (size_t)b * SEQ * HD + (size_t)kt * KVB * HD;
  #pragma unroll
  for (int i = 0; i < 8; ++i) {
    int idx = tid + i * 256;
    int r = idx >> 6, c = idx & 63;
    *(f32x4*)&Lt[r][c * 4] = *(const f32x4*)&hb[(size_t)r * HD + c * 4];
  }
  __syncthreads();
  unsigned short* vpt = vp + (size_t)(b * 64 + kt) * 16384;
  #pragma unroll
  for (int i = 0; i < 4; ++i) {
    int chunk = tid + i * 256;            // 0..1023
    int ht = chunk >> 6, l = chunk & 63;
    union { s16x8 v; unsigned short u[8]; } uh, ul;
    #pragma unroll
    for (int e = 0; e < 8; ++e) {
      float f = Lt[(l >> 4) * 8 + e][ht * 16 + (l & 15)];
      cvt_hilo(f, uh.u[e], ul.u[e]);
    }
    *(s16x8*)&vpt[(size_t)(ht * 2) * 512 + l * 8] = uh.v;
    *(s16x8*)&vpt[(size_t)(ht * 2 + 1) * 512 + l * 8] = ul.v;
  }
}

// ---------------- K4 v4 (round-11, MEASURED BEST): LDS-staged bf16x3 flash
// attn, K+V pre-packed. DISPROVEN alternatives (do not retry): r9 split-K
// waves from global (4x L2 traffic + merge), r12 barrier-free direct-global
// (LDS staging is a 4x traffic amplifier across the WG's waves — barriers
// pay for load sharing; tail 616->827 without them).
__global__ __launch_bounds__(256, 1) void attention_kernel(
    const float* __restrict__ all_h, const unsigned short* __restrict__ kp,
    const unsigned short* __restrict__ vp, float* __restrict__ ctxg) {
  __shared__ __align__(16) unsigned short KU[32 * 512];
  __shared__ __align__(16) unsigned short VU[32 * 512];
  __shared__ __align__(16) unsigned short PB[4][2][520];
  const int b = blockIdx.y, qb = blockIdx.x;
  int tid = threadIdx.x, lane = tid & 63, wv = tid >> 6;
  int lm = lane & 15, kg = lane >> 4;
  const float* hb = all_h + (size_t)b * SEQ * HD;
  const unsigned short* kpb = kp + (size_t)b * 64 * 16384;
  const unsigned short* vpb = vp + (size_t)b * 64 * 16384;
  const int q0 = qb * 64 + wv * 16;        // wave's 16 q-rows

  // Q fragments (hi/lo): lane holds Q[q0+lm][ch*32 + kg*8 + e]
  s16x8 Qh[8], Ql[8];
  {
    const float* qp = hb + (size_t)(q0 + lm) * HD;
    #pragma unroll
    for (int ch = 0; ch < 8; ++ch) {
      union { s16x8 v; unsigned short u[8]; } uh, ul;
      f32x4 a0 = *(const f32x4*)&qp[ch * 32 + kg * 8];
      f32x4 a1 = *(const f32x4*)&qp[ch * 32 + kg * 8 + 4];
      #pragma unroll
      for (int e = 0; e < 4; ++e) {
        cvt_hilo(a0[e], uh.u[e], ul.u[e]);
        cvt_hilo(a1[e], uh.u[4 + e], ul.u[4 + e]);
      }
      Qh[ch] = uh.v; Ql[ch] = ul.v;
    }
  }

  f32x4 co[16];
  #pragma unroll
  for (int ht = 0; ht < 16; ++ht) co[ht] = (f32x4){0.f, 0.f, 0.f, 0.f};
  float mo[4] = {-3e38f, -3e38f, -3e38f, -3e38f};
  float lr[4] = {0.f, 0.f, 0.f, 0.f};

  const int nkt = 2 * qb + 2;
  s16x8 kp8[8], vp8[8];                    // prefetch regs (64 VGPR)
  #pragma unroll
  for (int i = 0; i < 8; ++i) {
    int up = wv + i * 4;                   // wave-uniform unit-plane
    kp8[i] = *(const s16x8*)&kpb[(size_t)up * 512 + lane * 8];
    vp8[i] = *(const s16x8*)&vpb[(size_t)up * 512 + lane * 8];
  }
  for (int kt = 0; kt < nkt; ++kt) {
    __syncthreads();                       // prev tile consumed
    #pragma unroll
    for (int i = 0; i < 8; ++i) {          // linear b128 writes, no cvt
      int up = wv + i * 4;
      *(s16x8*)&KU[up * 512 + lane * 8] = kp8[i];
      *(s16x8*)&VU[up * 512 + lane * 8] = vp8[i];
    }
    __syncthreads();                       // tile ready
    if (kt + 1 < nkt) {                    // prefetch kt+1 under compute
      const unsigned short* tk = kpb + (size_t)(kt + 1) * 16384;
      const unsigned short* tv = vpb + (size_t)(kt + 1) * 16384;
      #pragma unroll
      for (int i = 0; i < 8; ++i) {
        int up = wv + i * 4;
        kp8[i] = *(const s16x8*)&tk[(size_t)up * 512 + lane * 8];
        vp8[i] = *(const s16x8*)&tv[(size_t)up * 512 + lane * 8];
      }
    }
    int k0 = kt * KVB;

    // ---- QK^T: two 16-key groups, 3 hi/lo terms each
    float s[4][2];
    #pragma unroll
    for (int g = 0; g < 2; ++g) {
      f32x4 a0 = {0.f,0.f,0.f,0.f}, a1 = {0.f,0.f,0.f,0.f}, a2 = {0.f,0.f,0.f,0.f};
      #pragma unroll
      for (int ch = 0; ch < 8; ++ch) {
        const unsigned short* ub = &KU[((g * 8 + ch) * 2) * 512 + lane * 8];
        s16x8 bh = *(const s16x8*)ub;
        s16x8 bl = *(const s16x8*)(ub + 512);
        a0 = __builtin_amdgcn_mfma_f32_16x16x32_bf16(Qh[ch], bh, a0, 0, 0, 0);
        a1 = __builtin_amdgcn_mfma_f32_16x16x32_bf16(Ql[ch], bh, a1, 0, 0, 0);
        a2 = __builtin_amdgcn_mfma_f32_16x16x32_bf16(Qh[ch], bl, a2, 0, 0, 0);
      }
      #pragma unroll
      for (int r = 0; r < 4; ++r) s[r][g] = a0[r] + a1[r] + a2[r];
    }
    // ---- online softmax (q-row = kg*4+r; keys k0+lm, k0+16+lm)
    float p[4][2], al[4];
    #pragma unroll
    for (int r = 0; r < 4; ++r) {
      int qrow = q0 + kg * 4 + r;
      int va = (k0 + lm) <= qrow, vb = (k0 + 16 + lm) <= qrow;
      float ta = va ? s[r][0] : -3e38f;
      float tb = vb ? s[r][1] : -3e38f;
      float t = fmaxf(ta, tb);
      t = fmaxf(t, __shfl_xor(t, 1));
      t = fmaxf(t, __shfl_xor(t, 2));
      t = fmaxf(t, __shfl_xor(t, 4));
      t = fmaxf(t, __shfl_xor(t, 8));
      float mn = fmaxf(mo[r], t);
      al[r] = __expf(mo[r] - mn);
      float pa = va ? __expf(s[r][0] - mn) : 0.f;
      float pb = vb ? __expf(s[r][1] - mn) : 0.f;
      p[r][0] = pa; p[r][1] = pb;
      float rs = pa + pb;
      rs += __shfl_xor(rs, 1);
      rs += __shfl_xor(rs, 2);
      rs += __shfl_xor(rs, 4);
      rs += __shfl_xor(rs, 8);
      lr[r] = lr[r] * al[r] + rs;
      mo[r] = mn;
    }
    // ---- P -> A-frag via per-wave LDS (wave-internal, no barrier)
    #pragma unroll
    for (int r = 0; r < 4; ++r)
      #pragma unroll
      for (int g = 0; g < 2; ++g) {
        unsigned short ph, pl;
        cvt_hilo(p[r][g], ph, pl);
        int key = g * 16 + lm;
        int o = ((key >> 3) * 16 + kg * 4 + r) * 8 + (key & 7);
        PB[wv][0][o] = ph;
        PB[wv][1][o] = pl;
      }
    s16x8 pah = *(const s16x8*)&PB[wv][0][lane * 8];
    s16x8 pal = *(const s16x8*)&PB[wv][1][lane * 8];
    // ---- rescale + PV (full 32-key K-dim per MFMA)
    #pragma unroll
    for (int ht = 0; ht < 16; ++ht) {
      f32x4 c = co[ht];
      #pragma unroll
      for (int r = 0; r < 4; ++r) c[r] *= al[r];
      const unsigned short* vb2 = &VU[(ht * 2) * 512 + lane * 8];
      s16x8 vh = *(const s16x8*)vb2;
      s16x8 vl = *(const s16x8*)(vb2 + 512);
      c = __builtin_amdgcn_mfma_f32_16x16x32_bf16(pah, vh, c, 0, 0, 0);
      c = __builtin_amdgcn_mfma_f32_16x16x32_bf16(pah, vl, c, 0, 0, 0);
      c = __builtin_amdgcn_mfma_f32_16x16x32_bf16(pal, vh, c, 0, 0, 0);
      co[ht] = c;
    }
  }
  float li[4];
  #pragma unroll
  for (int r = 0; r < 4; ++r) li[r] = rcp_fast(lr[r]);
  #pragma unroll
  for (int ht = 0; ht < 16; ++ht)
    #pragma unroll
    for (int r = 0; r < 4; ++r)
      ctxg[((size_t)b * SEQ + q0 + kg * 4 + r) * HD + ht * 16 + lm] = co[ht][r] * li[r];
}

// ---------------- comb GEMM: A = [all_h | ctx] split-K (K=512), tanh epilogue
__global__ __launch_bounds__(256) void gemm_bias_cat(
    const float* __restrict__ A1, const float* __restrict__ A2,
    const float* __restrict__ W, const float* __restrict__ bias,
    float* __restrict__ C) {
  __shared__ float As[128][36];
  __shared__ float Ws[64][36];
  const int K = 512;
  int tid = threadIdx.x;
  int m0 = blockIdx.y * 128, n0 = blockIdx.x * 64;
  int ml = tid & 31, g = tid >> 5;
  float acc[4][8];
  #pragma unroll
  for (int i = 0; i < 4; ++i)
    #pragma unroll
    for (int jj = 0; jj < 8; ++jj) acc[i][jj] = 0.f;
  for (int k0 = 0; k0 < K; k0 += 32) {
    const float* src = (k0 < 256) ? A1 : A2;
    int kb = (k0 < 256) ? k0 : k0 - 256;
    __syncthreads();
    #pragma unroll
    for (int i = 0; i < 4; ++i) {
      int idx = tid + i * 256;
      int r = idx >> 3, c4 = (idx & 7) * 4;
      *(f32x4*)&As[r][c4] = *(const f32x4*)&src[(size_t)(m0 + r) * 256 + kb + c4];
    }
    #pragma unroll
    for (int i = 0; i < 2; ++i) {
      int idx = tid + i * 256;
      int r = idx >> 3, c4 = (idx & 7) * 4;
      *(f32x4*)&Ws[r][c4] = *(const f32x4*)&W[(size_t)(n0 + r) * K + k0 + c4];
    }
    __syncthreads();
    #pragma unroll
    for (int k4 = 0; k4 < 32; k4 += 4) {
      f32x4 av[4], wv8[8];
      #pragma unroll
      for (int i = 0; i < 4; ++i) av[i] = *(const f32x4*)&As[ml + i * 32][k4];
      #pragma unroll
      for (int jj = 0; jj < 8; ++jj) wv8[jj] = *(const f32x4*)&Ws[g * 8 + jj][k4];
      #pragma unroll
      for (int kk = 0; kk < 4; ++kk)
        #pragma unroll
        for (int i = 0; i < 4; ++i)
          #pragma unroll
          for (int jj = 0; jj < 8; ++jj)
            acc[i][jj] += av[i][kk] * wv8[jj][kk];
    }
  }
  #pragma unroll
  for (int i = 0; i < 4; ++i) {
    int m = m0 + ml + i * 32;
    #pragma unroll
    for (int jj = 0; jj < 8; ++jj) {
      int n = n0 + g * 8 + jj;
      C[(size_t)m * 256 + n] = tanh_fast(acc[i][jj] + bias[n]);
    }
  }
}

extern "C" void kernel_launch(void* const* d_in, const int* in_sizes, int n_in,
                              void* d_out, int out_size, void* d_ws, size_t ws_size,
                              hipStream_t stream) {
  (void)in_sizes; (void)n_in; (void)out_size; (void)ws_size;
  const int*   x      = (const int*)  d_in[0];
  const float* emb    = (const float*)d_in[1];
  const float* w_ih   = (const float*)d_in[2];
  const float* w_hh   = (const float*)d_in[3];
  const float* b_ih   = (const float*)d_in[4];
  const float* b_hh   = (const float*)d_in[5];
  const float* attn_w = (const float*)d_in[6];
  const float* attn_b = (const float*)d_in[7];
  const float* comb_w = (const float*)d_in[8];
  const float* comb_b = (const float*)d_in[9];
  const float* fc_w   = (const float*)d_in[10];
  const float* fc_b   = (const float*)d_in[11];
  float* out = (float*)d_out;

  // workspace (floats): table | all_h | kp(packed K) | ctx | vp(packed V)
  float* ws    = (float*)d_ws;
  float* table = ws;                        // 100*256*4    =   102400
  float* all_h = table + 102400;            // 16384*256    =  4194304
  float* keysb = all_h + 4194304;           //               4194304 (shorts: packed K; later combined)
  float* ctx   = keysb + 4194304;           //               4194304
  float* vbuf  = ctx + 4194304;             //               4194304 (shorts: packed V)
  float* hlast = out + (size_t)NB * SEQ * NV;
  unsigned short* kpack = (unsigned short*)keysb;
  unsigned short* vpack = (unsigned short*)vbuf;

  build_table<<<100, 256, 0, stream>>>(emb, w_ih, b_ih, table);
  gru_scan<<<NB, 512, 0, stream>>>(x, w_hh, b_hh, table, all_h, hlast);
  // packed keys = pack(all_h @ attn_w^T + attn_b)
  gemm_keys_pack<<<dim3(4, 128), 256, 0, stream>>>(all_h, attn_w, attn_b, kpack);
  // packed V = pack(all_h)
  pack_v<<<dim3(64, NB), 256, 0, stream>>>(all_h, vpack);
  // ctx = softmax(causal(all_h @ keys^T)) @ all_h   (bf16x3 MFMA flash attn)
  attention_kernel<<<dim3(32, NB), 256, 0, stream>>>(all_h, kpack, vpack, ctx);
  // combined = tanh([all_h|ctx] @ comb_w^T + comb_b)  (into keys buffer region)
  gemm_bias_cat<<<dim3(4, 128), 256, 0, stream>>>(all_h, ctx, comb_w, comb_b, keysb);
  // out = combined @ fc_w^T + fc_b
  gemm_bias<0><<<dim3(2, 128), 256, 0, stream>>>(keysb, 256, fc_w, fc_b, out, 100, 100, 256);
}